// Round 5
// baseline (484.957 us; speedup 1.0000x reference)
//
#include <hip/hip_runtime.h>

#define N_NODES 50000
#define W_IN    256
#define W_OUT   256
#define HEADS   8
#define NUM_T   3
#define N_EDGES 800000
#define NEG_SLOPE 0.2f

#define NB      128           // coarse buckets (98 used)
#define BSH     9             // bucket = dst >> 9  (512 nodes/bucket)
#define BNODES  512
#define P1_EPT  16            // edges per thread in partition kernels
#define P1_CHUNK (256 * P1_EPT)   // 4096 edges per block
#define P1_BLOCKS ((N_EDGES + P1_CHUNK - 1) / P1_CHUNK)  // 196
#define NB_USED ((N_NODES + BNODES - 1) / BNODES)        // 98

#define GEMM_BLOCKS ((N_NODES + 63) / 64)       // 782
#define GATHER_BLOCKS ((N_NODES + 3) / 4)       // 12500
// smem carve: Cs[64][264] bf16 @0 (33792 B, overlaps As@0/Bs@5120 which are
// dead after the K loop), els @33792 (2048), ers @35840 (2048).
#define GEMM_SMEM 37888

typedef __attribute__((ext_vector_type(8))) short bf16x8;
typedef __attribute__((ext_vector_type(4))) float f32x4;

__device__ __forceinline__ unsigned short f2b(float f) {
    unsigned u = __float_as_uint(f);
    u = (u + 0x7fffu + ((u >> 16) & 1u)) >> 16;
    return (unsigned short)u;
}
__device__ __forceinline__ float blo(unsigned u) { return __uint_as_float(u << 16); }
__device__ __forceinline__ float bhi(unsigned u) { return __uint_as_float(u & 0xffff0000u); }

// ---------------------------------------------------------------------------
// x fp32 -> bf16 (RNE). 12500 blocks * 256 threads * 4 elems = 12.8M exact.
// ---------------------------------------------------------------------------
__global__ __launch_bounds__(256) void convert_x(const float* __restrict__ x,
                                                 unsigned short* __restrict__ xb) {
    const size_t i = ((size_t)blockIdx.x * 256 + threadIdx.x) * 4;
    const float4 v = *(const float4*)(x + i);
    ushort4 o;
    o.x = f2b(v.x); o.y = f2b(v.y); o.z = f2b(v.z); o.w = f2b(v.w);
    *(ushort4*)(xb + i) = o;
}

// ---------------------------------------------------------------------------
// W fp32 [t][k][n] -> bf16 transposed [t][n][k].
// ---------------------------------------------------------------------------
__global__ __launch_bounds__(256) void convert_W(const float* __restrict__ Wsrc,
                                                 unsigned short* __restrict__ Wt) {
    const int t = blockIdx.y;
    const int gid = blockIdx.x * 256 + threadIdx.x;  // 0..65535
    const int k = gid >> 8, n = gid & 255;
    Wt[(size_t)t * 65536 + (size_t)n * 256 + k] = f2b(Wsrc[(size_t)t * 65536 + gid]);
}

// ---------------------------------------------------------------------------
// Partition level 1a: coarse histogram (LDS-aggregated).
// ---------------------------------------------------------------------------
__global__ __launch_bounds__(256) void p1_hist(const int* __restrict__ adj,
                                               int* __restrict__ bucket_cnt) {
    __shared__ int lh[NB];
    const int t = blockIdx.y;
    const int tid = threadIdx.x;
    if (tid < NB) lh[tid] = 0;
    __syncthreads();

    const int* dstp = adj + (size_t)t * 2 * N_EDGES + N_EDGES;
    const int e0 = blockIdx.x * P1_CHUNK + tid * P1_EPT;
#pragma unroll
    for (int i = 0; i < P1_EPT; ++i) {
        const int e = e0 + i;
        if (e < N_EDGES) atomicAdd(&lh[dstp[e] >> BSH], 1);
    }
    __syncthreads();
    if (tid < NB && lh[tid] > 0) atomicAdd(&bucket_cnt[t * NB + tid], lh[tid]);
}

// ---------------------------------------------------------------------------
// Partition level 1b: scan 128 bucket counts per type. One block, 128 thr.
// ---------------------------------------------------------------------------
__global__ __launch_bounds__(128) void p1_scan(const int* __restrict__ bucket_cnt,
                                               int* __restrict__ bucket_ptr,
                                               int* __restrict__ bucket_cur) {
    __shared__ int s[NB];
    const int tid = threadIdx.x;
    for (int t = 0; t < NUM_T; ++t) {
        const int v = bucket_cnt[t * NB + tid];
        s[tid] = v;
        __syncthreads();
        for (int off = 1; off < NB; off <<= 1) {
            int o = (tid >= off) ? s[tid - off] : 0;
            __syncthreads();
            s[tid] += o;
            __syncthreads();
        }
        const int incl = s[tid];
        const int excl = incl - v;
        bucket_ptr[t * (NB + 1) + tid] = excl;
        bucket_cur[t * NB + tid] = excl;
        if (tid == NB - 1) bucket_ptr[t * (NB + 1) + NB] = incl;
        __syncthreads();
    }
}

// ---------------------------------------------------------------------------
// Partition level 1c v2: LDS counting-sort, then contiguous flush.
// ---------------------------------------------------------------------------
__global__ __launch_bounds__(256) void p1_scatter(const int* __restrict__ adj,
                                                  int* __restrict__ bucket_cur,
                                                  uint2* __restrict__ part) {
    __shared__ int lh[NB];
    __shared__ int loff[NB];
    __shared__ int lbase[NB];
    __shared__ uint2 buf[P1_CHUNK];   // 32 KB
    const int t = blockIdx.y;
    const int tid = threadIdx.x;
    const int lane = tid & 63;
    const int wave = tid >> 6;
    if (tid < NB) lh[tid] = 0;
    __syncthreads();

    const int* srcp = adj + (size_t)t * 2 * N_EDGES;
    const int* dstp = srcp + N_EDGES;
    const int e0 = blockIdx.x * P1_CHUNK + tid * P1_EPT;

    int es[P1_EPT], ed[P1_EPT], rk[P1_EPT];
#pragma unroll
    for (int i = 0; i < P1_EPT; ++i) {
        const int e = e0 + i;
        if (e < N_EDGES) {
            es[i] = srcp[e];
            ed[i] = dstp[e];
            rk[i] = atomicAdd(&lh[ed[i] >> BSH], 1);
        } else {
            ed[i] = -1;
        }
    }
    __syncthreads();

    // global window reserve (one atomic per non-empty bucket)
    if (tid < NB && lh[tid] > 0)
        lbase[tid] = atomicAdd(&bucket_cur[t * NB + tid], lh[tid]);
    // local exclusive scan of lh -> loff (wave 0, 2 buckets/lane)
    if (wave == 0) {
        const int c0 = lh[lane * 2], c1 = lh[lane * 2 + 1];
        const int s = c0 + c1;
        int run = s;
        for (int off = 1; off < 64; off <<= 1) {
            const int o = __shfl_up(run, off);
            if (lane >= off) run += o;
        }
        const int base = run - s;
        loff[lane * 2] = base;
        loff[lane * 2 + 1] = base + c0;
    }
    __syncthreads();

#pragma unroll
    for (int i = 0; i < P1_EPT; ++i)
        if (ed[i] >= 0)
            buf[loff[ed[i] >> BSH] + rk[i]] =
                make_uint2((unsigned)es[i], (unsigned)ed[i]);
    __syncthreads();

    uint2* pt = part + (size_t)t * N_EDGES;
    int nvalid = N_EDGES - blockIdx.x * P1_CHUNK;
    if (nvalid > P1_CHUNK) nvalid = P1_CHUNK;
    for (int idx = tid; idx < nvalid; idx += 256) {
        const uint2 e = buf[idx];
        const int b = (int)(e.y >> BSH);
        pt[lbase[b] + (idx - loff[b])] = e;
    }
}

// ---------------------------------------------------------------------------
// Partition level 2: per-bucket local CSR. One block per (bucket, type).
// ---------------------------------------------------------------------------
__global__ __launch_bounds__(256) void p2_csr(const uint2* __restrict__ part,
                                              const int* __restrict__ bucket_ptr,
                                              int* __restrict__ row_ptr_all,
                                              int* __restrict__ csr_all) {
    __shared__ int sc[BNODES];
    const int b = blockIdx.x;
    const int t = blockIdx.y;
    const int tid = threadIdx.x;
    const int lane = tid & 63;
    const int wave = tid >> 6;

    const uint2* pt = part + (size_t)t * N_EDGES;
    int* row_ptr = row_ptr_all + (size_t)t * (N_NODES + 1);
    int* csr = csr_all + (size_t)t * N_EDGES;

    const int bp0 = bucket_ptr[t * (NB + 1) + b];
    const int bp1 = bucket_ptr[t * (NB + 1) + b + 1];
    const int node0 = b * BNODES;
    int nn = N_NODES - node0; if (nn > BNODES) nn = BNODES;

    sc[tid] = 0; sc[tid + 256] = 0;
    __syncthreads();

    for (int idx = bp0 + tid; idx < bp1; idx += 256)
        atomicAdd(&sc[pt[idx].y - node0], 1);
    __syncthreads();

    if (wave == 0) {
        int v[8], ex[8];
        int s = 0;
#pragma unroll
        for (int i = 0; i < 8; ++i) { v[i] = sc[lane * 8 + i]; ex[i] = s; s += v[i]; }
        int run = s;
        for (int off = 1; off < 64; off <<= 1) {
            int o = __shfl_up(run, off);
            if (lane >= off) run += o;
        }
        const int base = run - s;
#pragma unroll
        for (int i = 0; i < 8; ++i) sc[lane * 8 + i] = base + ex[i];
    }
    __syncthreads();

    for (int i = tid; i < nn; i += 256) row_ptr[node0 + i] = bp0 + sc[i];
    if (b == NB_USED - 1 && tid == 0) row_ptr[N_NODES] = N_EDGES;
    __syncthreads();

    for (int idx = bp0 + tid; idx < bp1; idx += 256) {
        const uint2 e = pt[idx];
        const int pos = bp0 + atomicAdd(&sc[e.y - node0], 1);
        csr[pos] = (int)e.x;
    }
}

// ---------------------------------------------------------------------------
// GEMM + fused attention-score body.
// Round-5 change: C-tile staged to LDS (bf16 [64][264], +8-col pad) and H
// written as 8x uint4 per thread (512 B/wave-inst, coalesced) instead of 64
// scalar ushort stores per thread (store-issue serialization, ~60 us chip-wide).
// ---------------------------------------------------------------------------
__device__ __forceinline__ void gemm_body(const int bm, const int tid,
                                          unsigned char* smem,
                                          const unsigned short* __restrict__ xb,
                                          const unsigned short* __restrict__ Wt,
                                          const float* __restrict__ al,
                                          const float* __restrict__ ar,
                                          unsigned short* __restrict__ H,
                                          float* __restrict__ el,
                                          float* __restrict__ er) {
    unsigned short* As = (unsigned short*)smem;
    unsigned short* Bs = (unsigned short*)(smem + 5120);
    float* els = (float*)(smem + 33792);
    float* ers = (float*)(smem + 35840);

    const int wave = tid >> 6;
    const int lane = tid & 63;
    const int quad = lane >> 4;
    const int l16 = lane & 15;
    const int m0 = bm * 64;

    f32x4 acc[4][4] = {};

    const int arow = tid >> 2;
    const int achunk = (tid & 3) * 8;
    int gm = m0 + arow;
    if (gm > N_NODES - 1) gm = N_NODES - 1;
    const unsigned short* aptr = xb + (size_t)gm * W_IN + achunk;

    for (int k0 = 0; k0 < W_IN; k0 += 32) {
        const uint4 av = *(const uint4*)(aptr + k0);
        *(uint4*)&As[arow * 40 + achunk] = av;
#pragma unroll
        for (int i = 0; i < 4; ++i) {
            const int idx = i * 256 + tid;
            const int brow = idx >> 2;
            const int bch = (idx & 3) * 8;
            const uint4 bv = *(const uint4*)(Wt + (size_t)brow * W_IN + k0 + bch);
            *(uint4*)&Bs[brow * 40 + bch] = bv;
        }
        __syncthreads();

        bf16x8 af[4], bfr[4];
#pragma unroll
        for (int mi = 0; mi < 4; ++mi)
            af[mi] = *(const bf16x8*)&As[(mi * 16 + l16) * 40 + quad * 8];
#pragma unroll
        for (int ni = 0; ni < 4; ++ni)
            bfr[ni] = *(const bf16x8*)&Bs[(wave * 64 + ni * 16 + l16) * 40 + quad * 8];
#pragma unroll
        for (int mi = 0; mi < 4; ++mi)
#pragma unroll
            for (int ni = 0; ni < 4; ++ni)
                acc[mi][ni] = __builtin_amdgcn_mfma_f32_16x16x32_bf16(
                    af[mi], bfr[ni], acc[mi][ni], 0, 0, 0);
        __syncthreads();
    }

    // ---- stage C tile -> LDS (bf16), then vectorized H write ----
    {
        unsigned short* Cs = (unsigned short*)smem;   // [64][264], reuses As/Bs
#pragma unroll
        for (int mi = 0; mi < 4; ++mi)
#pragma unroll
            for (int ni = 0; ni < 4; ++ni)
#pragma unroll
                for (int reg = 0; reg < 4; ++reg)
                    Cs[(mi * 16 + quad * 4 + reg) * 264 + wave * 64 + ni * 16 + l16] =
                        f2b(acc[mi][ni][reg]);
        __syncthreads();
        const int row = tid >> 2;        // 0..63
        const int c0 = (tid & 3) * 64;   // 64-col chunk per thread (128 B)
        const int gr = m0 + row;
        if (gr < N_NODES) {
            unsigned short* hp = H + (size_t)gr * W_OUT + c0;
            const unsigned short* cp = &Cs[row * 264 + c0];
#pragma unroll
            for (int j = 0; j < 8; ++j)
                *(uint4*)(hp + j * 8) = *(const uint4*)(cp + j * 8);
        }
        __syncthreads();   // Cs reads done before any later smem reuse
    }

    float al4[4], ar4[4];
#pragma unroll
    for (int ni = 0; ni < 4; ++ni) {
        const int c = wave * 64 + ni * 16 + l16;
        al4[ni] = al[c];
        ar4[ni] = ar[c];
    }
#pragma unroll
    for (int mi = 0; mi < 4; ++mi) {
        float pl[4][2] = {}, pr[4][2] = {};
#pragma unroll
        for (int ni = 0; ni < 4; ++ni) {
            const int hl = ni >> 1;
#pragma unroll
            for (int reg = 0; reg < 4; ++reg) {
                pl[reg][hl] += acc[mi][ni][reg] * al4[ni];
                pr[reg][hl] += acc[mi][ni][reg] * ar4[ni];
            }
        }
#pragma unroll
        for (int off = 1; off < 16; off <<= 1)
#pragma unroll
            for (int reg = 0; reg < 4; ++reg)
#pragma unroll
                for (int hl = 0; hl < 2; ++hl) {
                    pl[reg][hl] += __shfl_xor(pl[reg][hl], off);
                    pr[reg][hl] += __shfl_xor(pr[reg][hl], off);
                }
        if (l16 == 0)
#pragma unroll
            for (int reg = 0; reg < 4; ++reg)
#pragma unroll
                for (int hl = 0; hl < 2; ++hl) {
                    const int row = mi * 16 + quad * 4 + reg;
                    els[row * 8 + wave * 2 + hl] = pl[reg][hl];
                    ers[row * 8 + wave * 2 + hl] = pr[reg][hl];
                }
    }
    __syncthreads();

    int nn = N_NODES - m0; if (nn > 64) nn = 64;
    const int nn8 = nn * 8;
    const int i = tid * 4;
    if (i < nn8) {
        *(float4*)(el + (size_t)m0 * 8 + i) = *(float4*)&els[i];
        *(float4*)(er + (size_t)m0 * 8 + i) = *(float4*)&ers[i];
    }
}

__global__ __launch_bounds__(256) void gemm_fused(const unsigned short* __restrict__ xb,
                                                  const unsigned short* __restrict__ Wt,
                                                  const float* __restrict__ al,
                                                  const float* __restrict__ ar,
                                                  unsigned short* __restrict__ H,
                                                  float* __restrict__ el,
                                                  float* __restrict__ er) {
    __shared__ __attribute__((aligned(16))) unsigned char smem[GEMM_SMEM];
    const size_t t = blockIdx.y;
    gemm_body(blockIdx.x, threadIdx.x, smem, xb,
              Wt + t * 65536, al + t * 256, ar + t * 256,
              H + t * (size_t)N_NODES * W_OUT,
              el + t * (size_t)N_NODES * HEADS,
              er + t * (size_t)N_NODES * HEADS);
}

// ---------------------------------------------------------------------------
// Gather v3 inner loop (proven 2-edge + 1-deep pipeline) accumulating into
// caller-owned registers. No epilogue here.
// ---------------------------------------------------------------------------
__device__ __forceinline__ void gather_accum(const int node, const int lane,
                                             const int* __restrict__ csr_src,
                                             const int* __restrict__ row_ptr,
                                             const float* __restrict__ el,
                                             const float* __restrict__ er,
                                             const unsigned short* __restrict__ H,
                                             float2 (&acc)[4], float& ssum) {
    const int half = lane >> 5;
    const int d8 = lane & 31;
    const int hh = d8 >> 2;

    const int beg = row_ptr[node];
    const int deg = row_ptr[node + 1] - beg;
    if (deg <= 0) return;
    const float erv = er[(size_t)node * HEADS + hh];

    int mysrc = (lane < deg) ? csr_src[beg + lane] : 0;
    const int npairs = (deg + 1) >> 1;

    // prologue: load pair 0 (edge ei = half)
    int src0 = __shfl(mysrc, half);
    uint4 u0 = *(const uint4*)(H + (size_t)src0 * W_OUT + d8 * 8);
    float elv0 = el[(size_t)src0 * HEADS + hh];

    for (int q = 0; q < npairs; ++q) {
        int src1 = 0; uint4 u1 = u0; float elv1 = 0.f;
        const int q1 = q + 1;
        if (q1 < npairs) {
            if ((q1 & 31) == 0) {
                const int cb = beg + (q1 >> 5) * 64;
                mysrc = (cb + lane < beg + deg) ? csr_src[cb + lane] : 0;
            }
            src1 = __shfl(mysrc, (2 * q1 + half) & 63);
            u1 = *(const uint4*)(H + (size_t)src1 * W_OUT + d8 * 8);
            elv1 = el[(size_t)src1 * HEADS + hh];
        }
        float v = elv0 + erv;
        v = (v > 0.f) ? v : NEG_SLOPE * v;
        const float w = (2 * q + half < deg) ? __expf(v) : 0.f;
        acc[0].x += w * blo(u0.x); acc[0].y += w * bhi(u0.x);
        acc[1].x += w * blo(u0.y); acc[1].y += w * bhi(u0.y);
        acc[2].x += w * blo(u0.z); acc[2].y += w * bhi(u0.z);
        acc[3].x += w * blo(u0.w); acc[3].y += w * bhi(u0.w);
        ssum += w;
        src0 = src1; u0 = u1; elv0 = elv1;
    }
}

// ---------------------------------------------------------------------------
// Gather for all 3 edge types + fused semantic-attention combine.
// ---------------------------------------------------------------------------
__global__ __launch_bounds__(256) void gat_gather_all(
    const int* __restrict__ csr_src, const int* __restrict__ row_ptr,
    const float* __restrict__ el, const float* __restrict__ er,
    const unsigned short* __restrict__ H,
    const float* __restrict__ bias, const float* __restrict__ att_w,
    const float* __restrict__ att_b, float* __restrict__ out) {
    const int node = (blockIdx.x * blockDim.x + threadIdx.x) >> 6;
    const int lane = threadIdx.x & 63;
    if (node >= N_NODES) return;

    float2 acc[NUM_T][4] = {};
    float ssum[NUM_T] = {};

#pragma unroll
    for (int t = 0; t < NUM_T; ++t)
        gather_accum(node, lane,
                     csr_src + (size_t)t * N_EDGES,
                     row_ptr + (size_t)t * (N_NODES + 1),
                     el + (size_t)t * N_NODES * HEADS,
                     er + (size_t)t * N_NODES * HEADS,
                     H + (size_t)t * N_NODES * W_OUT,
                     acc[t], ssum[t]);

    // cross-half reduce (lane ^ 32)
#pragma unroll
    for (int t = 0; t < NUM_T; ++t) {
#pragma unroll
        for (int i = 0; i < 4; ++i) {
            acc[t][i].x += __shfl_xor(acc[t][i].x, 32);
            acc[t][i].y += __shfl_xor(acc[t][i].y, 32);
        }
        ssum[t] += __shfl_xor(ssum[t], 32);
    }

    const int half = lane >> 5;
    const int d8 = lane & 31;
    if (half == 0) {
        const float4 aw0 = *(const float4*)(att_w + d8 * 8);
        const float4 aw1 = *(const float4*)(att_w + d8 * 8 + 4);
        float h[NUM_T][8];
        float p[NUM_T];
#pragma unroll
        for (int t = 0; t < NUM_T; ++t) {
            const float inv = 1.f / (ssum[t] + 1e-9f);
            const float4 b0 = *(const float4*)(bias + t * W_OUT + d8 * 8);
            const float4 b1 = *(const float4*)(bias + t * W_OUT + d8 * 8 + 4);
            h[t][0] = acc[t][0].x * inv + b0.x;
            h[t][1] = acc[t][0].y * inv + b0.y;
            h[t][2] = acc[t][1].x * inv + b0.z;
            h[t][3] = acc[t][1].y * inv + b0.w;
            h[t][4] = acc[t][2].x * inv + b1.x;
            h[t][5] = acc[t][2].y * inv + b1.y;
            h[t][6] = acc[t][3].x * inv + b1.z;
            h[t][7] = acc[t][3].y * inv + b1.w;
            p[t] = h[t][0] * aw0.x + h[t][1] * aw0.y + h[t][2] * aw0.z +
                   h[t][3] * aw0.w + h[t][4] * aw1.x + h[t][5] * aw1.y +
                   h[t][6] * aw1.z + h[t][7] * aw1.w;
        }
        // reduce semantic scores over the 32 active lanes
#pragma unroll
        for (int off = 1; off < 32; off <<= 1) {
            p[0] += __shfl_xor(p[0], off);
            p[1] += __shfl_xor(p[1], off);
            p[2] += __shfl_xor(p[2], off);
        }
        const float ab = att_b[0];
        const float a0 = p[0] + ab, a1 = p[1] + ab, a2 = p[2] + ab;
        float4 o0, o1;
        o0.x = a0 * h[0][0] + a1 * h[1][0] + a2 * h[2][0];
        o0.y = a0 * h[0][1] + a1 * h[1][1] + a2 * h[2][1];
        o0.z = a0 * h[0][2] + a1 * h[1][2] + a2 * h[2][2];
        o0.w = a0 * h[0][3] + a1 * h[1][3] + a2 * h[2][3];
        o1.x = a0 * h[0][4] + a1 * h[1][4] + a2 * h[2][4];
        o1.y = a0 * h[0][5] + a1 * h[1][5] + a2 * h[2][5];
        o1.z = a0 * h[0][6] + a1 * h[1][6] + a2 * h[2][6];
        o1.w = a0 * h[0][7] + a1 * h[1][7] + a2 * h[2][7];
        *(float4*)(out + (size_t)node * W_OUT + d8 * 8) = o0;
        *(float4*)(out + (size_t)node * W_OUT + d8 * 8 + 4) = o1;
    }
}

// ---------------------------------------------------------------------------
extern "C" void kernel_launch(void* const* d_in, const int* in_sizes, int n_in,
                              void* d_out, int out_size, void* d_ws, size_t ws_size,
                              hipStream_t stream) {
    const float* x     = (const float*)d_in[0];
    const int*   adj   = (const int*)d_in[1];   // [3][2][N_EDGES]
    const float* Ws    = (const float*)d_in[2]; // [3][256][256]
    const float* a_l   = (const float*)d_in[3]; // [3][8][32]
    const float* a_r   = (const float*)d_in[4];
    const float* bias  = (const float*)d_in[5]; // [3][256]
    const float* att_w = (const float*)d_in[6]; // [256]
    const float* att_b = (const float*)d_in[7]; // [1]
    float* out = (float*)d_out;

    // Workspace (~123 MB). part (19.2 MB) aliases H[0]: part is consumed by
    // p2_csr BEFORE gemm_fused writes H (single stream, serial dispatches).
    char* w = (char*)d_ws;
    unsigned short* xb = (unsigned short*)w; w += (size_t)N_NODES * W_IN * 2;          // 25.6 MB
    unsigned short* H  = (unsigned short*)w; w += (size_t)NUM_T * N_NODES * W_OUT * 2; // 76.8 MB
    unsigned short* Wt = (unsigned short*)w; w += (size_t)NUM_T * 65536 * 2;           // 0.39 MB
    float* el = (float*)w; w += (size_t)NUM_T * N_NODES * HEADS * 4;   // 4.8 MB
    float* er = (float*)w; w += (size_t)NUM_T * N_NODES * HEADS * 4;   // 4.8 MB
    int* csr_src = (int*)w; w += (size_t)NUM_T * N_EDGES * 4;          // 9.6 MB
    int* row_ptr = (int*)w; w += (size_t)NUM_T * (N_NODES + 1) * 4;
    int* bucket_cnt = (int*)w; w += NUM_T * NB * 4;
    int* bucket_ptr = (int*)w; w += NUM_T * (NB + 1) * 4;
    int* bucket_cur = (int*)w; w += NUM_T * NB * 4;
    uint2* part = (uint2*)H;   // 19.2 MB alias into H[0]

    // --- setup: converts + two-level CSR build (all types at once) ---
    hipMemsetAsync(bucket_cnt, 0, NUM_T * NB * sizeof(int), stream);
    convert_x<<<12500, 256, 0, stream>>>(x, xb);
    convert_W<<<dim3(256, NUM_T), 256, 0, stream>>>(Ws, Wt);
    p1_hist<<<dim3(P1_BLOCKS, NUM_T), 256, 0, stream>>>(adj, bucket_cnt);
    p1_scan<<<1, 128, 0, stream>>>(bucket_cnt, bucket_ptr, bucket_cur);
    p1_scatter<<<dim3(P1_BLOCKS, NUM_T), 256, 0, stream>>>(adj, bucket_cur, part);
    p2_csr<<<dim3(NB_USED, NUM_T), 256, 0, stream>>>(part, bucket_ptr, row_ptr,
                                                     csr_src);

    // --- all 3 gemms in one dispatch (H overwrites the part alias) ---
    gemm_fused<<<dim3(GEMM_BLOCKS, NUM_T), 256, 0, stream>>>(
        xb, Wt, a_l, a_r, H, el, er);

    // --- gather all types + semantic combine fused, fp32 out ---
    gat_gather_all<<<GATHER_BLOCKS, 256, 0, stream>>>(
        csr_src, row_ptr, el, er, H, bias, att_w, att_b, out);
}

// Round 6
// 467.216 us; speedup vs baseline: 1.0380x; 1.0380x over previous
//
#include <hip/hip_runtime.h>

#define N_NODES 50000
#define W_IN    256
#define W_OUT   256
#define HEADS   8
#define NUM_T   3
#define N_EDGES 800000
#define NEG_SLOPE 0.2f

#define NB      128           // coarse buckets (98 used)
#define BSH     9             // bucket = dst >> 9  (512 nodes/bucket)
#define BNODES  512
#define P1_EPT  16            // edges per thread in partition kernels
#define P1_CHUNK (256 * P1_EPT)   // 4096 edges per block
#define P1_BLOCKS ((N_EDGES + P1_CHUNK - 1) / P1_CHUNK)  // 196
#define NB_USED ((N_NODES + BNODES - 1) / BNODES)        // 98

#define GEMM_BLOCKS ((N_NODES + 63) / 64)       // 782
#define GATHER_BLOCKS ((N_NODES + 3) / 4)       // 12500
#define GEMM_SMEM 25600   // As 5120 + Bs 20480 (el/er epilogue removed)

typedef __attribute__((ext_vector_type(8))) short bf16x8;
typedef __attribute__((ext_vector_type(4))) float f32x4;

__device__ __forceinline__ unsigned short f2b(float f) {
    unsigned u = __float_as_uint(f);
    u = (u + 0x7fffu + ((u >> 16) & 1u)) >> 16;
    return (unsigned short)u;
}
__device__ __forceinline__ float blo(unsigned u) { return __uint_as_float(u << 16); }
__device__ __forceinline__ float bhi(unsigned u) { return __uint_as_float(u & 0xffff0000u); }

// ---------------------------------------------------------------------------
// x fp32 -> bf16 (RNE). 12500 blocks * 256 threads * 4 elems = 12.8M exact.
// ---------------------------------------------------------------------------
__global__ __launch_bounds__(256) void convert_x(const float* __restrict__ x,
                                                 unsigned short* __restrict__ xb) {
    const size_t i = ((size_t)blockIdx.x * 256 + threadIdx.x) * 4;
    const float4 v = *(const float4*)(x + i);
    ushort4 o;
    o.x = f2b(v.x); o.y = f2b(v.y); o.z = f2b(v.z); o.w = f2b(v.w);
    *(ushort4*)(xb + i) = o;
}

// ---------------------------------------------------------------------------
// W fp32 [t][k][n] -> bf16 transposed [t][n][k].
// ---------------------------------------------------------------------------
__global__ __launch_bounds__(256) void convert_W(const float* __restrict__ Wsrc,
                                                 unsigned short* __restrict__ Wt) {
    const int t = blockIdx.y;
    const int gid = blockIdx.x * 256 + threadIdx.x;  // 0..65535
    const int k = gid >> 8, n = gid & 255;
    Wt[(size_t)t * 65536 + (size_t)n * 256 + k] = f2b(Wsrc[(size_t)t * 65536 + gid]);
}

// ---------------------------------------------------------------------------
// Partition level 1a: coarse histogram (LDS-aggregated).
// ---------------------------------------------------------------------------
__global__ __launch_bounds__(256) void p1_hist(const int* __restrict__ adj,
                                               int* __restrict__ bucket_cnt) {
    __shared__ int lh[NB];
    const int t = blockIdx.y;
    const int tid = threadIdx.x;
    if (tid < NB) lh[tid] = 0;
    __syncthreads();

    const int* dstp = adj + (size_t)t * 2 * N_EDGES + N_EDGES;
    const int e0 = blockIdx.x * P1_CHUNK + tid * P1_EPT;
#pragma unroll
    for (int i = 0; i < P1_EPT; ++i) {
        const int e = e0 + i;
        if (e < N_EDGES) atomicAdd(&lh[dstp[e] >> BSH], 1);
    }
    __syncthreads();
    if (tid < NB && lh[tid] > 0) atomicAdd(&bucket_cnt[t * NB + tid], lh[tid]);
}

// ---------------------------------------------------------------------------
// Partition level 1b: scan 128 bucket counts per type. One block, 128 thr.
// ---------------------------------------------------------------------------
__global__ __launch_bounds__(128) void p1_scan(const int* __restrict__ bucket_cnt,
                                               int* __restrict__ bucket_ptr,
                                               int* __restrict__ bucket_cur) {
    __shared__ int s[NB];
    const int tid = threadIdx.x;
    for (int t = 0; t < NUM_T; ++t) {
        const int v = bucket_cnt[t * NB + tid];
        s[tid] = v;
        __syncthreads();
        for (int off = 1; off < NB; off <<= 1) {
            int o = (tid >= off) ? s[tid - off] : 0;
            __syncthreads();
            s[tid] += o;
            __syncthreads();
        }
        const int incl = s[tid];
        const int excl = incl - v;
        bucket_ptr[t * (NB + 1) + tid] = excl;
        bucket_cur[t * NB + tid] = excl;
        if (tid == NB - 1) bucket_ptr[t * (NB + 1) + NB] = incl;
        __syncthreads();
    }
}

// ---------------------------------------------------------------------------
// Partition level 1c v2: LDS counting-sort, then contiguous flush.
// ---------------------------------------------------------------------------
__global__ __launch_bounds__(256) void p1_scatter(const int* __restrict__ adj,
                                                  int* __restrict__ bucket_cur,
                                                  uint2* __restrict__ part) {
    __shared__ int lh[NB];
    __shared__ int loff[NB];
    __shared__ int lbase[NB];
    __shared__ uint2 buf[P1_CHUNK];   // 32 KB
    const int t = blockIdx.y;
    const int tid = threadIdx.x;
    const int lane = tid & 63;
    const int wave = tid >> 6;
    if (tid < NB) lh[tid] = 0;
    __syncthreads();

    const int* srcp = adj + (size_t)t * 2 * N_EDGES;
    const int* dstp = srcp + N_EDGES;
    const int e0 = blockIdx.x * P1_CHUNK + tid * P1_EPT;

    int es[P1_EPT], ed[P1_EPT], rk[P1_EPT];
#pragma unroll
    for (int i = 0; i < P1_EPT; ++i) {
        const int e = e0 + i;
        if (e < N_EDGES) {
            es[i] = srcp[e];
            ed[i] = dstp[e];
            rk[i] = atomicAdd(&lh[ed[i] >> BSH], 1);
        } else {
            ed[i] = -1;
        }
    }
    __syncthreads();

    // global window reserve (one atomic per non-empty bucket)
    if (tid < NB && lh[tid] > 0)
        lbase[tid] = atomicAdd(&bucket_cur[t * NB + tid], lh[tid]);
    // local exclusive scan of lh -> loff (wave 0, 2 buckets/lane)
    if (wave == 0) {
        const int c0 = lh[lane * 2], c1 = lh[lane * 2 + 1];
        const int s = c0 + c1;
        int run = s;
        for (int off = 1; off < 64; off <<= 1) {
            const int o = __shfl_up(run, off);
            if (lane >= off) run += o;
        }
        const int base = run - s;
        loff[lane * 2] = base;
        loff[lane * 2 + 1] = base + c0;
    }
    __syncthreads();

#pragma unroll
    for (int i = 0; i < P1_EPT; ++i)
        if (ed[i] >= 0)
            buf[loff[ed[i] >> BSH] + rk[i]] =
                make_uint2((unsigned)es[i], (unsigned)ed[i]);
    __syncthreads();

    uint2* pt = part + (size_t)t * N_EDGES;
    int nvalid = N_EDGES - blockIdx.x * P1_CHUNK;
    if (nvalid > P1_CHUNK) nvalid = P1_CHUNK;
    for (int idx = tid; idx < nvalid; idx += 256) {
        const uint2 e = buf[idx];
        const int b = (int)(e.y >> BSH);
        pt[lbase[b] + (idx - loff[b])] = e;
    }
}

// ---------------------------------------------------------------------------
// Partition level 2: per-bucket local CSR. One block per (bucket, type).
// ---------------------------------------------------------------------------
__global__ __launch_bounds__(256) void p2_csr(const uint2* __restrict__ part,
                                              const int* __restrict__ bucket_ptr,
                                              int* __restrict__ row_ptr_all,
                                              int* __restrict__ csr_all) {
    __shared__ int sc[BNODES];
    const int b = blockIdx.x;
    const int t = blockIdx.y;
    const int tid = threadIdx.x;
    const int lane = tid & 63;
    const int wave = tid >> 6;

    const uint2* pt = part + (size_t)t * N_EDGES;
    int* row_ptr = row_ptr_all + (size_t)t * (N_NODES + 1);
    int* csr = csr_all + (size_t)t * N_EDGES;

    const int bp0 = bucket_ptr[t * (NB + 1) + b];
    const int bp1 = bucket_ptr[t * (NB + 1) + b + 1];
    const int node0 = b * BNODES;
    int nn = N_NODES - node0; if (nn > BNODES) nn = BNODES;

    sc[tid] = 0; sc[tid + 256] = 0;
    __syncthreads();

    for (int idx = bp0 + tid; idx < bp1; idx += 256)
        atomicAdd(&sc[pt[idx].y - node0], 1);
    __syncthreads();

    if (wave == 0) {
        int v[8], ex[8];
        int s = 0;
#pragma unroll
        for (int i = 0; i < 8; ++i) { v[i] = sc[lane * 8 + i]; ex[i] = s; s += v[i]; }
        int run = s;
        for (int off = 1; off < 64; off <<= 1) {
            int o = __shfl_up(run, off);
            if (lane >= off) run += o;
        }
        const int base = run - s;
#pragma unroll
        for (int i = 0; i < 8; ++i) sc[lane * 8 + i] = base + ex[i];
    }
    __syncthreads();

    for (int i = tid; i < nn; i += 256) row_ptr[node0 + i] = bp0 + sc[i];
    if (b == NB_USED - 1 && tid == 0) row_ptr[N_NODES] = N_EDGES;
    __syncthreads();

    for (int idx = bp0 + tid; idx < bp1; idx += 256) {
        const uint2 e = pt[idx];
        const int pos = bp0 + atomicAdd(&sc[e.y - node0], 1);
        csr[pos] = (int)e.x;
    }
}

// ---------------------------------------------------------------------------
// GEMM body, pure H = xb @ Wt^T. The el/er epilogue (256 shfl_xor on the DS
// pipe per thread, ~35% of kernel time) moved to compute_elr (memory-bound).
// C-store: round-4 proven scalar stores (round-5 LDS staging was a regression).
// ---------------------------------------------------------------------------
__device__ __forceinline__ void gemm_body(const int bm, const int tid,
                                          unsigned char* smem,
                                          const unsigned short* __restrict__ xb,
                                          const unsigned short* __restrict__ Wt,
                                          unsigned short* __restrict__ H) {
    unsigned short* As = (unsigned short*)smem;
    unsigned short* Bs = (unsigned short*)(smem + 5120);

    const int wave = tid >> 6;
    const int lane = tid & 63;
    const int quad = lane >> 4;
    const int l16 = lane & 15;
    const int m0 = bm * 64;

    f32x4 acc[4][4] = {};

    const int arow = tid >> 2;
    const int achunk = (tid & 3) * 8;
    int gm = m0 + arow;
    if (gm > N_NODES - 1) gm = N_NODES - 1;
    const unsigned short* aptr = xb + (size_t)gm * W_IN + achunk;

    for (int k0 = 0; k0 < W_IN; k0 += 32) {
        const uint4 av = *(const uint4*)(aptr + k0);
        *(uint4*)&As[arow * 40 + achunk] = av;
#pragma unroll
        for (int i = 0; i < 4; ++i) {
            const int idx = i * 256 + tid;
            const int brow = idx >> 2;
            const int bch = (idx & 3) * 8;
            const uint4 bv = *(const uint4*)(Wt + (size_t)brow * W_IN + k0 + bch);
            *(uint4*)&Bs[brow * 40 + bch] = bv;
        }
        __syncthreads();

        bf16x8 af[4], bfr[4];
#pragma unroll
        for (int mi = 0; mi < 4; ++mi)
            af[mi] = *(const bf16x8*)&As[(mi * 16 + l16) * 40 + quad * 8];
#pragma unroll
        for (int ni = 0; ni < 4; ++ni)
            bfr[ni] = *(const bf16x8*)&Bs[(wave * 64 + ni * 16 + l16) * 40 + quad * 8];
#pragma unroll
        for (int mi = 0; mi < 4; ++mi)
#pragma unroll
            for (int ni = 0; ni < 4; ++ni)
                acc[mi][ni] = __builtin_amdgcn_mfma_f32_16x16x32_bf16(
                    af[mi], bfr[ni], acc[mi][ni], 0, 0, 0);
        __syncthreads();
    }

#pragma unroll
    for (int mi = 0; mi < 4; ++mi)
#pragma unroll
        for (int reg = 0; reg < 4; ++reg) {
            const int gr = m0 + mi * 16 + quad * 4 + reg;
            if (gr < N_NODES)
#pragma unroll
                for (int ni = 0; ni < 4; ++ni)
                    H[(size_t)gr * W_OUT + wave * 64 + ni * 16 + l16] =
                        f2b(acc[mi][ni][reg]);
        }
}

__global__ __launch_bounds__(256) void gemm_fused(const unsigned short* __restrict__ xb,
                                                  const unsigned short* __restrict__ Wt,
                                                  unsigned short* __restrict__ H) {
    __shared__ __attribute__((aligned(16))) unsigned char smem[GEMM_SMEM];
    const size_t t = blockIdx.y;
    gemm_body(blockIdx.x, threadIdx.x, smem, xb,
              Wt + t * 65536,
              H + t * (size_t)N_NODES * W_OUT);
}

// ---------------------------------------------------------------------------
// el/er as a memory-bound row-scan of H (L3-resident): one wave per node.
// lane = head*8 + j8; each lane dots 4 cols of its head with a_l/a_r, then
// 3-level shfl_xor within the 8-lane head group. el[t][n][h], er likewise.
// ---------------------------------------------------------------------------
__global__ __launch_bounds__(256) void compute_elr(
    const unsigned short* __restrict__ H, const float* __restrict__ a_l,
    const float* __restrict__ a_r, float* __restrict__ el,
    float* __restrict__ er) {
    const int node = (blockIdx.x * blockDim.x + threadIdx.x) >> 6;
    if (node >= N_NODES) return;
    const int t = blockIdx.y;
    const int lane = threadIdx.x & 63;
    const int h = lane >> 3;       // head 0..7
    const int j8 = lane & 7;       // 8 lanes per head, 4 cols each

    const size_t row = (size_t)t * N_NODES + node;
    const uint2 u = *(const uint2*)(H + row * W_OUT + h * 32 + j8 * 4);
    const float4 av = *(const float4*)(a_l + t * 256 + h * 32 + j8 * 4);
    const float4 rv = *(const float4*)(a_r + t * 256 + h * 32 + j8 * 4);
    const float c0 = blo(u.x), c1 = bhi(u.x), c2 = blo(u.y), c3 = bhi(u.y);
    float pl = c0 * av.x + c1 * av.y + c2 * av.z + c3 * av.w;
    float pr = c0 * rv.x + c1 * rv.y + c2 * rv.z + c3 * rv.w;
#pragma unroll
    for (int off = 1; off < 8; off <<= 1) {
        pl += __shfl_xor(pl, off);
        pr += __shfl_xor(pr, off);
    }
    if (j8 == 0) el[row * HEADS + h] = pl;
    if (j8 == 1) er[row * HEADS + h] = pr;
}

// ---------------------------------------------------------------------------
// Gather v3 inner loop (proven 2-edge + 1-deep pipeline) accumulating into
// caller-owned registers. No epilogue here.
// ---------------------------------------------------------------------------
__device__ __forceinline__ void gather_accum(const int node, const int lane,
                                             const int* __restrict__ csr_src,
                                             const int* __restrict__ row_ptr,
                                             const float* __restrict__ el,
                                             const float* __restrict__ er,
                                             const unsigned short* __restrict__ H,
                                             float2 (&acc)[4], float& ssum) {
    const int half = lane >> 5;
    const int d8 = lane & 31;
    const int hh = d8 >> 2;

    const int beg = row_ptr[node];
    const int deg = row_ptr[node + 1] - beg;
    if (deg <= 0) return;
    const float erv = er[(size_t)node * HEADS + hh];

    int mysrc = (lane < deg) ? csr_src[beg + lane] : 0;
    const int npairs = (deg + 1) >> 1;

    // prologue: load pair 0 (edge ei = half)
    int src0 = __shfl(mysrc, half);
    uint4 u0 = *(const uint4*)(H + (size_t)src0 * W_OUT + d8 * 8);
    float elv0 = el[(size_t)src0 * HEADS + hh];

    for (int q = 0; q < npairs; ++q) {
        int src1 = 0; uint4 u1 = u0; float elv1 = 0.f;
        const int q1 = q + 1;
        if (q1 < npairs) {
            if ((q1 & 31) == 0) {
                const int cb = beg + (q1 >> 5) * 64;
                mysrc = (cb + lane < beg + deg) ? csr_src[cb + lane] : 0;
            }
            src1 = __shfl(mysrc, (2 * q1 + half) & 63);
            u1 = *(const uint4*)(H + (size_t)src1 * W_OUT + d8 * 8);
            elv1 = el[(size_t)src1 * HEADS + hh];
        }
        float v = elv0 + erv;
        v = (v > 0.f) ? v : NEG_SLOPE * v;
        const float w = (2 * q + half < deg) ? __expf(v) : 0.f;
        acc[0].x += w * blo(u0.x); acc[0].y += w * bhi(u0.x);
        acc[1].x += w * blo(u0.y); acc[1].y += w * bhi(u0.y);
        acc[2].x += w * blo(u0.z); acc[2].y += w * bhi(u0.z);
        acc[3].x += w * blo(u0.w); acc[3].y += w * bhi(u0.w);
        ssum += w;
        src0 = src1; u0 = u1; elv0 = elv1;
    }
}

// ---------------------------------------------------------------------------
// Gather for all 3 edge types + fused semantic-attention combine.
// ---------------------------------------------------------------------------
__global__ __launch_bounds__(256) void gat_gather_all(
    const int* __restrict__ csr_src, const int* __restrict__ row_ptr,
    const float* __restrict__ el, const float* __restrict__ er,
    const unsigned short* __restrict__ H,
    const float* __restrict__ bias, const float* __restrict__ att_w,
    const float* __restrict__ att_b, float* __restrict__ out) {
    const int node = (blockIdx.x * blockDim.x + threadIdx.x) >> 6;
    const int lane = threadIdx.x & 63;
    if (node >= N_NODES) return;

    float2 acc[NUM_T][4] = {};
    float ssum[NUM_T] = {};

#pragma unroll
    for (int t = 0; t < NUM_T; ++t)
        gather_accum(node, lane,
                     csr_src + (size_t)t * N_EDGES,
                     row_ptr + (size_t)t * (N_NODES + 1),
                     el + (size_t)t * N_NODES * HEADS,
                     er + (size_t)t * N_NODES * HEADS,
                     H + (size_t)t * N_NODES * W_OUT,
                     acc[t], ssum[t]);

    // cross-half reduce (lane ^ 32)
#pragma unroll
    for (int t = 0; t < NUM_T; ++t) {
#pragma unroll
        for (int i = 0; i < 4; ++i) {
            acc[t][i].x += __shfl_xor(acc[t][i].x, 32);
            acc[t][i].y += __shfl_xor(acc[t][i].y, 32);
        }
        ssum[t] += __shfl_xor(ssum[t], 32);
    }

    const int half = lane >> 5;
    const int d8 = lane & 31;
    if (half == 0) {
        const float4 aw0 = *(const float4*)(att_w + d8 * 8);
        const float4 aw1 = *(const float4*)(att_w + d8 * 8 + 4);
        float h[NUM_T][8];
        float p[NUM_T];
#pragma unroll
        for (int t = 0; t < NUM_T; ++t) {
            const float inv = 1.f / (ssum[t] + 1e-9f);
            const float4 b0 = *(const float4*)(bias + t * W_OUT + d8 * 8);
            const float4 b1 = *(const float4*)(bias + t * W_OUT + d8 * 8 + 4);
            h[t][0] = acc[t][0].x * inv + b0.x;
            h[t][1] = acc[t][0].y * inv + b0.y;
            h[t][2] = acc[t][1].x * inv + b0.z;
            h[t][3] = acc[t][1].y * inv + b0.w;
            h[t][4] = acc[t][2].x * inv + b1.x;
            h[t][5] = acc[t][2].y * inv + b1.y;
            h[t][6] = acc[t][3].x * inv + b1.z;
            h[t][7] = acc[t][3].y * inv + b1.w;
            p[t] = h[t][0] * aw0.x + h[t][1] * aw0.y + h[t][2] * aw0.z +
                   h[t][3] * aw0.w + h[t][4] * aw1.x + h[t][5] * aw1.y +
                   h[t][6] * aw1.z + h[t][7] * aw1.w;
        }
        // reduce semantic scores over the 32 active lanes
#pragma unroll
        for (int off = 1; off < 32; off <<= 1) {
            p[0] += __shfl_xor(p[0], off);
            p[1] += __shfl_xor(p[1], off);
            p[2] += __shfl_xor(p[2], off);
        }
        const float ab = att_b[0];
        const float a0 = p[0] + ab, a1 = p[1] + ab, a2 = p[2] + ab;
        float4 o0, o1;
        o0.x = a0 * h[0][0] + a1 * h[1][0] + a2 * h[2][0];
        o0.y = a0 * h[0][1] + a1 * h[1][1] + a2 * h[2][1];
        o0.z = a0 * h[0][2] + a1 * h[1][2] + a2 * h[2][2];
        o0.w = a0 * h[0][3] + a1 * h[1][3] + a2 * h[2][3];
        o1.x = a0 * h[0][4] + a1 * h[1][4] + a2 * h[2][4];
        o1.y = a0 * h[0][5] + a1 * h[1][5] + a2 * h[2][5];
        o1.z = a0 * h[0][6] + a1 * h[1][6] + a2 * h[2][6];
        o1.w = a0 * h[0][7] + a1 * h[1][7] + a2 * h[2][7];
        *(float4*)(out + (size_t)node * W_OUT + d8 * 8) = o0;
        *(float4*)(out + (size_t)node * W_OUT + d8 * 8 + 4) = o1;
    }
}

// ---------------------------------------------------------------------------
extern "C" void kernel_launch(void* const* d_in, const int* in_sizes, int n_in,
                              void* d_out, int out_size, void* d_ws, size_t ws_size,
                              hipStream_t stream) {
    const float* x     = (const float*)d_in[0];
    const int*   adj   = (const int*)d_in[1];   // [3][2][N_EDGES]
    const float* Ws    = (const float*)d_in[2]; // [3][256][256]
    const float* a_l   = (const float*)d_in[3]; // [3][8][32]
    const float* a_r   = (const float*)d_in[4];
    const float* bias  = (const float*)d_in[5]; // [3][256]
    const float* att_w = (const float*)d_in[6]; // [256]
    const float* att_b = (const float*)d_in[7]; // [1]
    float* out = (float*)d_out;

    // Workspace (~123 MB). part (19.2 MB) aliases H[0]: part is consumed by
    // p2_csr BEFORE gemm_fused writes H (single stream, serial dispatches).
    char* w = (char*)d_ws;
    unsigned short* xb = (unsigned short*)w; w += (size_t)N_NODES * W_IN * 2;          // 25.6 MB
    unsigned short* H  = (unsigned short*)w; w += (size_t)NUM_T * N_NODES * W_OUT * 2; // 76.8 MB
    unsigned short* Wt = (unsigned short*)w; w += (size_t)NUM_T * 65536 * 2;           // 0.39 MB
    float* el = (float*)w; w += (size_t)NUM_T * N_NODES * HEADS * 4;   // 4.8 MB
    float* er = (float*)w; w += (size_t)NUM_T * N_NODES * HEADS * 4;   // 4.8 MB
    int* csr_src = (int*)w; w += (size_t)NUM_T * N_EDGES * 4;          // 9.6 MB
    int* row_ptr = (int*)w; w += (size_t)NUM_T * (N_NODES + 1) * 4;
    int* bucket_cnt = (int*)w; w += NUM_T * NB * 4;
    int* bucket_ptr = (int*)w; w += NUM_T * (NB + 1) * 4;
    int* bucket_cur = (int*)w; w += NUM_T * NB * 4;
    uint2* part = (uint2*)H;   // 19.2 MB alias into H[0]

    // --- setup: converts + two-level CSR build (all types at once) ---
    hipMemsetAsync(bucket_cnt, 0, NUM_T * NB * sizeof(int), stream);
    convert_x<<<12500, 256, 0, stream>>>(x, xb);
    convert_W<<<dim3(256, NUM_T), 256, 0, stream>>>(Ws, Wt);
    p1_hist<<<dim3(P1_BLOCKS, NUM_T), 256, 0, stream>>>(adj, bucket_cnt);
    p1_scan<<<1, 128, 0, stream>>>(bucket_cnt, bucket_ptr, bucket_cur);
    p1_scatter<<<dim3(P1_BLOCKS, NUM_T), 256, 0, stream>>>(adj, bucket_cur, part);
    p2_csr<<<dim3(NB_USED, NUM_T), 256, 0, stream>>>(part, bucket_ptr, row_ptr,
                                                     csr_src);

    // --- all 3 gemms in one dispatch (H overwrites the part alias) ---
    gemm_fused<<<dim3(GEMM_BLOCKS, NUM_T), 256, 0, stream>>>(xb, Wt, H);

    // --- el/er from H (memory-bound, L3-resident) ---
    compute_elr<<<dim3(GATHER_BLOCKS, NUM_T), 256, 0, stream>>>(H, a_l, a_r,
                                                                el, er);

    // --- gather all types + semantic combine fused, fp32 out ---
    gat_gather_all<<<GATHER_BLOCKS, 256, 0, stream>>>(
        csr_src, row_ptr, el, er, H, bias, att_w, att_b, out);
}

// Round 7
// 462.791 us; speedup vs baseline: 1.0479x; 1.0096x over previous
//
#include <hip/hip_runtime.h>

#define N_NODES 50000
#define W_IN    256
#define W_OUT   256
#define HEADS   8
#define NUM_T   3
#define N_EDGES 800000
#define NEG_SLOPE 0.2f

#define NB      128           // coarse buckets (98 used)
#define BSH     9             // bucket = dst >> 9  (512 nodes/bucket)
#define BNODES  512
#define P1_EPT  16            // edges per thread in partition kernels
#define P1_CHUNK (256 * P1_EPT)   // 4096 edges per block
#define P1_BLOCKS ((N_EDGES + P1_CHUNK - 1) / P1_CHUNK)  // 196
#define NB_USED ((N_NODES + BNODES - 1) / BNODES)        // 98

#define MT_BLOCKS ((N_NODES + 127) / 128)   // 391 M-tiles
#define GATHER_BLOCKS ((N_NODES + 3) / 4)   // 12500

#if defined(__has_builtin)
#if __has_builtin(__builtin_amdgcn_global_load_lds)
#define HAS_GLL 1
#endif
#endif

typedef __attribute__((ext_vector_type(8))) short bf16x8;
typedef __attribute__((ext_vector_type(4))) float f32x4;

__device__ __forceinline__ unsigned short f2b(float f) {
    unsigned u = __float_as_uint(f);
    u = (u + 0x7fffu + ((u >> 16) & 1u)) >> 16;
    return (unsigned short)u;
}
__device__ __forceinline__ float blo(unsigned u) { return __uint_as_float(u << 16); }
__device__ __forceinline__ float bhi(unsigned u) { return __uint_as_float(u & 0xffff0000u); }

// ---------------------------------------------------------------------------
// x fp32 -> bf16 (RNE). 12500 blocks * 256 threads * 4 elems = 12.8M exact.
// ---------------------------------------------------------------------------
__global__ __launch_bounds__(256) void convert_x(const float* __restrict__ x,
                                                 unsigned short* __restrict__ xb) {
    const size_t i = ((size_t)blockIdx.x * 256 + threadIdx.x) * 4;
    const float4 v = *(const float4*)(x + i);
    ushort4 o;
    o.x = f2b(v.x); o.y = f2b(v.y); o.z = f2b(v.z); o.w = f2b(v.w);
    *(ushort4*)(xb + i) = o;
}

// ---------------------------------------------------------------------------
// W fp32 [t][k][n] -> bf16 transposed [t][n][k].
// ---------------------------------------------------------------------------
__global__ __launch_bounds__(256) void convert_W(const float* __restrict__ Wsrc,
                                                 unsigned short* __restrict__ Wt) {
    const int t = blockIdx.y;
    const int gid = blockIdx.x * 256 + threadIdx.x;  // 0..65535
    const int k = gid >> 8, n = gid & 255;
    Wt[(size_t)t * 65536 + (size_t)n * 256 + k] = f2b(Wsrc[(size_t)t * 65536 + gid]);
}

// ---------------------------------------------------------------------------
// Partition level 1a: coarse histogram (LDS-aggregated).
// ---------------------------------------------------------------------------
__global__ __launch_bounds__(256) void p1_hist(const int* __restrict__ adj,
                                               int* __restrict__ bucket_cnt) {
    __shared__ int lh[NB];
    const int t = blockIdx.y;
    const int tid = threadIdx.x;
    if (tid < NB) lh[tid] = 0;
    __syncthreads();

    const int* dstp = adj + (size_t)t * 2 * N_EDGES + N_EDGES;
    const int e0 = blockIdx.x * P1_CHUNK + tid * P1_EPT;
#pragma unroll
    for (int i = 0; i < P1_EPT; ++i) {
        const int e = e0 + i;
        if (e < N_EDGES) atomicAdd(&lh[dstp[e] >> BSH], 1);
    }
    __syncthreads();
    if (tid < NB && lh[tid] > 0) atomicAdd(&bucket_cnt[t * NB + tid], lh[tid]);
}

// ---------------------------------------------------------------------------
// Partition level 1b: scan 128 bucket counts per type. One block, 128 thr.
// ---------------------------------------------------------------------------
__global__ __launch_bounds__(128) void p1_scan(const int* __restrict__ bucket_cnt,
                                               int* __restrict__ bucket_ptr,
                                               int* __restrict__ bucket_cur) {
    __shared__ int s[NB];
    const int tid = threadIdx.x;
    for (int t = 0; t < NUM_T; ++t) {
        const int v = bucket_cnt[t * NB + tid];
        s[tid] = v;
        __syncthreads();
        for (int off = 1; off < NB; off <<= 1) {
            int o = (tid >= off) ? s[tid - off] : 0;
            __syncthreads();
            s[tid] += o;
            __syncthreads();
        }
        const int incl = s[tid];
        const int excl = incl - v;
        bucket_ptr[t * (NB + 1) + tid] = excl;
        bucket_cur[t * NB + tid] = excl;
        if (tid == NB - 1) bucket_ptr[t * (NB + 1) + NB] = incl;
        __syncthreads();
    }
}

// ---------------------------------------------------------------------------
// Partition level 1c v2: LDS counting-sort, then contiguous flush.
// ---------------------------------------------------------------------------
__global__ __launch_bounds__(256) void p1_scatter(const int* __restrict__ adj,
                                                  int* __restrict__ bucket_cur,
                                                  uint2* __restrict__ part) {
    __shared__ int lh[NB];
    __shared__ int loff[NB];
    __shared__ int lbase[NB];
    __shared__ uint2 buf[P1_CHUNK];   // 32 KB
    const int t = blockIdx.y;
    const int tid = threadIdx.x;
    const int lane = tid & 63;
    const int wave = tid >> 6;
    if (tid < NB) lh[tid] = 0;
    __syncthreads();

    const int* srcp = adj + (size_t)t * 2 * N_EDGES;
    const int* dstp = srcp + N_EDGES;
    const int e0 = blockIdx.x * P1_CHUNK + tid * P1_EPT;

    int es[P1_EPT], ed[P1_EPT], rk[P1_EPT];
#pragma unroll
    for (int i = 0; i < P1_EPT; ++i) {
        const int e = e0 + i;
        if (e < N_EDGES) {
            es[i] = srcp[e];
            ed[i] = dstp[e];
            rk[i] = atomicAdd(&lh[ed[i] >> BSH], 1);
        } else {
            ed[i] = -1;
        }
    }
    __syncthreads();

    // global window reserve (one atomic per non-empty bucket)
    if (tid < NB && lh[tid] > 0)
        lbase[tid] = atomicAdd(&bucket_cur[t * NB + tid], lh[tid]);
    // local exclusive scan of lh -> loff (wave 0, 2 buckets/lane)
    if (wave == 0) {
        const int c0 = lh[lane * 2], c1 = lh[lane * 2 + 1];
        const int s = c0 + c1;
        int run = s;
        for (int off = 1; off < 64; off <<= 1) {
            const int o = __shfl_up(run, off);
            if (lane >= off) run += o;
        }
        const int base = run - s;
        loff[lane * 2] = base;
        loff[lane * 2 + 1] = base + c0;
    }
    __syncthreads();

#pragma unroll
    for (int i = 0; i < P1_EPT; ++i)
        if (ed[i] >= 0)
            buf[loff[ed[i] >> BSH] + rk[i]] =
                make_uint2((unsigned)es[i], (unsigned)ed[i]);
    __syncthreads();

    uint2* pt = part + (size_t)t * N_EDGES;
    int nvalid = N_EDGES - blockIdx.x * P1_CHUNK;
    if (nvalid > P1_CHUNK) nvalid = P1_CHUNK;
    for (int idx = tid; idx < nvalid; idx += 256) {
        const uint2 e = buf[idx];
        const int b = (int)(e.y >> BSH);
        pt[lbase[b] + (idx - loff[b])] = e;
    }
}

// ---------------------------------------------------------------------------
// Partition level 2: per-bucket local CSR. One block per (bucket, type).
// ---------------------------------------------------------------------------
__global__ __launch_bounds__(256) void p2_csr(const uint2* __restrict__ part,
                                              const int* __restrict__ bucket_ptr,
                                              int* __restrict__ row_ptr_all,
                                              int* __restrict__ csr_all) {
    __shared__ int sc[BNODES];
    const int b = blockIdx.x;
    const int t = blockIdx.y;
    const int tid = threadIdx.x;
    const int lane = tid & 63;
    const int wave = tid >> 6;

    const uint2* pt = part + (size_t)t * N_EDGES;
    int* row_ptr = row_ptr_all + (size_t)t * (N_NODES + 1);
    int* csr = csr_all + (size_t)t * N_EDGES;

    const int bp0 = bucket_ptr[t * (NB + 1) + b];
    const int bp1 = bucket_ptr[t * (NB + 1) + b + 1];
    const int node0 = b * BNODES;
    int nn = N_NODES - node0; if (nn > BNODES) nn = BNODES;

    sc[tid] = 0; sc[tid + 256] = 0;
    __syncthreads();

    for (int idx = bp0 + tid; idx < bp1; idx += 256)
        atomicAdd(&sc[pt[idx].y - node0], 1);
    __syncthreads();

    if (wave == 0) {
        int v[8], ex[8];
        int s = 0;
#pragma unroll
        for (int i = 0; i < 8; ++i) { v[i] = sc[lane * 8 + i]; ex[i] = s; s += v[i]; }
        int run = s;
        for (int off = 1; off < 64; off <<= 1) {
            int o = __shfl_up(run, off);
            if (lane >= off) run += o;
        }
        const int base = run - s;
#pragma unroll
        for (int i = 0; i < 8; ++i) sc[lane * 8 + i] = base + ex[i];
    }
    __syncthreads();

    for (int i = tid; i < nn; i += 256) row_ptr[node0 + i] = bp0 + sc[i];
    if (b == NB_USED - 1 && tid == 0) row_ptr[N_NODES] = N_EDGES;
    __syncthreads();

    for (int idx = bp0 + tid; idx < bp1; idx += 256) {
        const uint2 e = pt[idx];
        const int pos = bp0 + atomicAdd(&sc[e.y - node0], 1);
        csr[pos] = (int)e.x;
    }
}

// ---------------------------------------------------------------------------
// GEMM (m97-style): 128x128 tile, BK=32, 4 waves (2x2 quadrants of 64x64),
// A/B staged via global_load_lds width=16 into linear [128][32] LDS (no pad;
// gl_lds writes wave-uniform-base + lane*16, so LDS order == lane order).
// Replaces the m33-style per-thread load->VGPR->ds_write staging (VALU-bound,
// MfmaUtil ~15% per m80 PMC of this pattern).
// ---------------------------------------------------------------------------
__global__ __launch_bounds__(256) void gemm_fused(const unsigned short* __restrict__ xb,
                                                  const unsigned short* __restrict__ Wt,
                                                  unsigned short* __restrict__ H) {
    __shared__ __attribute__((aligned(16))) unsigned short As[128 * 32];
    __shared__ __attribute__((aligned(16))) unsigned short Bs[128 * 32];

    const int tid  = threadIdx.x;
    const int wave = tid >> 6;
    const int lane = tid & 63;
    const int quad = lane >> 4;
    const int l16  = lane & 15;

    const int m0 = blockIdx.x * 128;
    const int n0 = blockIdx.y * 128;
    const int t  = blockIdx.z;

    const unsigned short* Bt = Wt + (size_t)t * 65536 + (size_t)n0 * W_IN;
    unsigned short* Hc = H + (size_t)t * N_NODES * W_OUT;

    const int moff = (wave >> 1) * 64;   // wave's row quadrant
    const int noff = (wave & 1) * 64;    // wave's col quadrant

    f32x4 acc[4][4] = {};

    // staging decomposition: chunk c = i*256 + tid; row = c>>2; 16B col = c&3.
    const int srow = tid >> 2;
    const int sch  = (tid & 3) * 8;      // bf16 col offset
    int ar0 = m0 + srow;       if (ar0 > N_NODES - 1) ar0 = N_NODES - 1;
    int ar1 = m0 + 64 + srow;  if (ar1 > N_NODES - 1) ar1 = N_NODES - 1;
    const unsigned short* a0p = xb + (size_t)ar0 * W_IN + sch;
    const unsigned short* a1p = xb + (size_t)ar1 * W_IN + sch;
    const unsigned short* b0p = Bt + (size_t)srow * W_IN + sch;
    const unsigned short* b1p = Bt + (size_t)(64 + srow) * W_IN + sch;
#if defined(HAS_GLL)
    const int ldso0 = wave * 64 * 8;          // elems: wave-uniform base, i=0
    const int ldso1 = (256 + wave * 64) * 8;  // i=1
#endif

    for (int k0 = 0; k0 < W_IN; k0 += 32) {
#if defined(HAS_GLL)
        __builtin_amdgcn_global_load_lds(
            (const __attribute__((address_space(1))) void*)(a0p + k0),
            (__attribute__((address_space(3))) void*)(As + ldso0), 16, 0, 0);
        __builtin_amdgcn_global_load_lds(
            (const __attribute__((address_space(1))) void*)(a1p + k0),
            (__attribute__((address_space(3))) void*)(As + ldso1), 16, 0, 0);
        __builtin_amdgcn_global_load_lds(
            (const __attribute__((address_space(1))) void*)(b0p + k0),
            (__attribute__((address_space(3))) void*)(Bs + ldso0), 16, 0, 0);
        __builtin_amdgcn_global_load_lds(
            (const __attribute__((address_space(1))) void*)(b1p + k0),
            (__attribute__((address_space(3))) void*)(Bs + ldso1), 16, 0, 0);
#else
        {   // fallback: per-thread staging to the same linear layout
            const uint4 av0 = *(const uint4*)(a0p + k0);
            const uint4 av1 = *(const uint4*)(a1p + k0);
            const uint4 bv0 = *(const uint4*)(b0p + k0);
            const uint4 bv1 = *(const uint4*)(b1p + k0);
            *(uint4*)&As[(size_t)tid * 8] = av0;
            *(uint4*)&As[2048 + (size_t)tid * 8] = av1;
            *(uint4*)&Bs[(size_t)tid * 8] = bv0;
            *(uint4*)&Bs[2048 + (size_t)tid * 8] = bv1;
        }
#endif
        __syncthreads();

        bf16x8 af[4], bfr[4];
#pragma unroll
        for (int mi = 0; mi < 4; ++mi)
            af[mi] = *(const bf16x8*)&As[(moff + mi * 16 + l16) * 32 + quad * 8];
#pragma unroll
        for (int ni = 0; ni < 4; ++ni)
            bfr[ni] = *(const bf16x8*)&Bs[(noff + ni * 16 + l16) * 32 + quad * 8];
#pragma unroll
        for (int mi = 0; mi < 4; ++mi)
#pragma unroll
            for (int ni = 0; ni < 4; ++ni)
                acc[mi][ni] = __builtin_amdgcn_mfma_f32_16x16x32_bf16(
                    af[mi], bfr[ni], acc[mi][ni], 0, 0, 0);
        __syncthreads();
    }

#pragma unroll
    for (int mi = 0; mi < 4; ++mi)
#pragma unroll
        for (int reg = 0; reg < 4; ++reg) {
            const int gr = m0 + moff + mi * 16 + quad * 4 + reg;
            if (gr < N_NODES)
#pragma unroll
                for (int ni = 0; ni < 4; ++ni)
                    Hc[(size_t)gr * W_OUT + n0 + noff + ni * 16 + l16] =
                        f2b(acc[mi][ni][reg]);
        }
}

// ---------------------------------------------------------------------------
// el/er as a memory-bound row-scan of H (L3-resident): one wave per node.
// ---------------------------------------------------------------------------
__global__ __launch_bounds__(256) void compute_elr(
    const unsigned short* __restrict__ H, const float* __restrict__ a_l,
    const float* __restrict__ a_r, float* __restrict__ el,
    float* __restrict__ er) {
    const int node = (blockIdx.x * blockDim.x + threadIdx.x) >> 6;
    if (node >= N_NODES) return;
    const int t = blockIdx.y;
    const int lane = threadIdx.x & 63;
    const int h = lane >> 3;       // head 0..7
    const int j8 = lane & 7;       // 8 lanes per head, 4 cols each

    const size_t row = (size_t)t * N_NODES + node;
    const uint2 u = *(const uint2*)(H + row * W_OUT + h * 32 + j8 * 4);
    const float4 av = *(const float4*)(a_l + t * 256 + h * 32 + j8 * 4);
    const float4 rv = *(const float4*)(a_r + t * 256 + h * 32 + j8 * 4);
    const float c0 = blo(u.x), c1 = bhi(u.x), c2 = blo(u.y), c3 = bhi(u.y);
    float pl = c0 * av.x + c1 * av.y + c2 * av.z + c3 * av.w;
    float pr = c0 * rv.x + c1 * rv.y + c2 * rv.z + c3 * rv.w;
#pragma unroll
    for (int off = 1; off < 8; off <<= 1) {
        pl += __shfl_xor(pl, off);
        pr += __shfl_xor(pr, off);
    }
    if (j8 == 0) el[row * HEADS + h] = pl;
    if (j8 == 1) er[row * HEADS + h] = pr;
}

// ---------------------------------------------------------------------------
// Gather v3 inner loop (proven 2-edge + 1-deep pipeline) accumulating into
// caller-owned registers. No epilogue here.
// ---------------------------------------------------------------------------
__device__ __forceinline__ void gather_accum(const int node, const int lane,
                                             const int* __restrict__ csr_src,
                                             const int* __restrict__ row_ptr,
                                             const float* __restrict__ el,
                                             const float* __restrict__ er,
                                             const unsigned short* __restrict__ H,
                                             float2 (&acc)[4], float& ssum) {
    const int half = lane >> 5;
    const int d8 = lane & 31;
    const int hh = d8 >> 2;

    const int beg = row_ptr[node];
    const int deg = row_ptr[node + 1] - beg;
    if (deg <= 0) return;
    const float erv = er[(size_t)node * HEADS + hh];

    int mysrc = (lane < deg) ? csr_src[beg + lane] : 0;
    const int npairs = (deg + 1) >> 1;

    // prologue: load pair 0 (edge ei = half)
    int src0 = __shfl(mysrc, half);
    uint4 u0 = *(const uint4*)(H + (size_t)src0 * W_OUT + d8 * 8);
    float elv0 = el[(size_t)src0 * HEADS + hh];

    for (int q = 0; q < npairs; ++q) {
        int src1 = 0; uint4 u1 = u0; float elv1 = 0.f;
        const int q1 = q + 1;
        if (q1 < npairs) {
            if ((q1 & 31) == 0) {
                const int cb = beg + (q1 >> 5) * 64;
                mysrc = (cb + lane < beg + deg) ? csr_src[cb + lane] : 0;
            }
            src1 = __shfl(mysrc, (2 * q1 + half) & 63);
            u1 = *(const uint4*)(H + (size_t)src1 * W_OUT + d8 * 8);
            elv1 = el[(size_t)src1 * HEADS + hh];
        }
        float v = elv0 + erv;
        v = (v > 0.f) ? v : NEG_SLOPE * v;
        const float w = (2 * q + half < deg) ? __expf(v) : 0.f;
        acc[0].x += w * blo(u0.x); acc[0].y += w * bhi(u0.x);
        acc[1].x += w * blo(u0.y); acc[1].y += w * bhi(u0.y);
        acc[2].x += w * blo(u0.z); acc[2].y += w * bhi(u0.z);
        acc[3].x += w * blo(u0.w); acc[3].y += w * bhi(u0.w);
        ssum += w;
        src0 = src1; u0 = u1; elv0 = elv1;
    }
}

// ---------------------------------------------------------------------------
// Gather for all 3 edge types + fused semantic-attention combine.
// ---------------------------------------------------------------------------
__global__ __launch_bounds__(256) void gat_gather_all(
    const int* __restrict__ csr_src, const int* __restrict__ row_ptr,
    const float* __restrict__ el, const float* __restrict__ er,
    const unsigned short* __restrict__ H,
    const float* __restrict__ bias, const float* __restrict__ att_w,
    const float* __restrict__ att_b, float* __restrict__ out) {
    const int node = (blockIdx.x * blockDim.x + threadIdx.x) >> 6;
    const int lane = threadIdx.x & 63;
    if (node >= N_NODES) return;

    float2 acc[NUM_T][4] = {};
    float ssum[NUM_T] = {};

#pragma unroll
    for (int t = 0; t < NUM_T; ++t)
        gather_accum(node, lane,
                     csr_src + (size_t)t * N_EDGES,
                     row_ptr + (size_t)t * (N_NODES + 1),
                     el + (size_t)t * N_NODES * HEADS,
                     er + (size_t)t * N_NODES * HEADS,
                     H + (size_t)t * N_NODES * W_OUT,
                     acc[t], ssum[t]);

    // cross-half reduce (lane ^ 32)
#pragma unroll
    for (int t = 0; t < NUM_T; ++t) {
#pragma unroll
        for (int i = 0; i < 4; ++i) {
            acc[t][i].x += __shfl_xor(acc[t][i].x, 32);
            acc[t][i].y += __shfl_xor(acc[t][i].y, 32);
        }
        ssum[t] += __shfl_xor(ssum[t], 32);
    }

    const int half = lane >> 5;
    const int d8 = lane & 31;
    if (half == 0) {
        const float4 aw0 = *(const float4*)(att_w + d8 * 8);
        const float4 aw1 = *(const float4*)(att_w + d8 * 8 + 4);
        float h[NUM_T][8];
        float p[NUM_T];
#pragma unroll
        for (int t = 0; t < NUM_T; ++t) {
            const float inv = 1.f / (ssum[t] + 1e-9f);
            const float4 b0 = *(const float4*)(bias + t * W_OUT + d8 * 8);
            const float4 b1 = *(const float4*)(bias + t * W_OUT + d8 * 8 + 4);
            h[t][0] = acc[t][0].x * inv + b0.x;
            h[t][1] = acc[t][0].y * inv + b0.y;
            h[t][2] = acc[t][1].x * inv + b0.z;
            h[t][3] = acc[t][1].y * inv + b0.w;
            h[t][4] = acc[t][2].x * inv + b1.x;
            h[t][5] = acc[t][2].y * inv + b1.y;
            h[t][6] = acc[t][3].x * inv + b1.z;
            h[t][7] = acc[t][3].y * inv + b1.w;
            p[t] = h[t][0] * aw0.x + h[t][1] * aw0.y + h[t][2] * aw0.z +
                   h[t][3] * aw0.w + h[t][4] * aw1.x + h[t][5] * aw1.y +
                   h[t][6] * aw1.z + h[t][7] * aw1.w;
        }
        // reduce semantic scores over the 32 active lanes
#pragma unroll
        for (int off = 1; off < 32; off <<= 1) {
            p[0] += __shfl_xor(p[0], off);
            p[1] += __shfl_xor(p[1], off);
            p[2] += __shfl_xor(p[2], off);
        }
        const float ab = att_b[0];
        const float a0 = p[0] + ab, a1 = p[1] + ab, a2 = p[2] + ab;
        float4 o0, o1;
        o0.x = a0 * h[0][0] + a1 * h[1][0] + a2 * h[2][0];
        o0.y = a0 * h[0][1] + a1 * h[1][1] + a2 * h[2][1];
        o0.z = a0 * h[0][2] + a1 * h[1][2] + a2 * h[2][2];
        o0.w = a0 * h[0][3] + a1 * h[1][3] + a2 * h[2][3];
        o1.x = a0 * h[0][4] + a1 * h[1][4] + a2 * h[2][4];
        o1.y = a0 * h[0][5] + a1 * h[1][5] + a2 * h[2][5];
        o1.z = a0 * h[0][6] + a1 * h[1][6] + a2 * h[2][6];
        o1.w = a0 * h[0][7] + a1 * h[1][7] + a2 * h[2][7];
        *(float4*)(out + (size_t)node * W_OUT + d8 * 8) = o0;
        *(float4*)(out + (size_t)node * W_OUT + d8 * 8 + 4) = o1;
    }
}

// ---------------------------------------------------------------------------
extern "C" void kernel_launch(void* const* d_in, const int* in_sizes, int n_in,
                              void* d_out, int out_size, void* d_ws, size_t ws_size,
                              hipStream_t stream) {
    const float* x     = (const float*)d_in[0];
    const int*   adj   = (const int*)d_in[1];   // [3][2][N_EDGES]
    const float* Ws    = (const float*)d_in[2]; // [3][256][256]
    const float* a_l   = (const float*)d_in[3]; // [3][8][32]
    const float* a_r   = (const float*)d_in[4];
    const float* bias  = (const float*)d_in[5]; // [3][256]
    const float* att_w = (const float*)d_in[6]; // [256]
    const float* att_b = (const float*)d_in[7]; // [1]
    float* out = (float*)d_out;

    // Workspace (~123 MB). part (19.2 MB) aliases H[0]: part is consumed by
    // p2_csr BEFORE gemm_fused writes H (single stream, serial dispatches).
    char* w = (char*)d_ws;
    unsigned short* xb = (unsigned short*)w; w += (size_t)N_NODES * W_IN * 2;          // 25.6 MB
    unsigned short* H  = (unsigned short*)w; w += (size_t)NUM_T * N_NODES * W_OUT * 2; // 76.8 MB
    unsigned short* Wt = (unsigned short*)w; w += (size_t)NUM_T * 65536 * 2;           // 0.39 MB
    float* el = (float*)w; w += (size_t)NUM_T * N_NODES * HEADS * 4;   // 4.8 MB
    float* er = (float*)w; w += (size_t)NUM_T * N_NODES * HEADS * 4;   // 4.8 MB
    int* csr_src = (int*)w; w += (size_t)NUM_T * N_EDGES * 4;          // 9.6 MB
    int* row_ptr = (int*)w; w += (size_t)NUM_T * (N_NODES + 1) * 4;
    int* bucket_cnt = (int*)w; w += NUM_T * NB * 4;
    int* bucket_ptr = (int*)w; w += NUM_T * (NB + 1) * 4;
    int* bucket_cur = (int*)w; w += NUM_T * NB * 4;
    uint2* part = (uint2*)H;   // 19.2 MB alias into H[0]

    // --- setup: converts + two-level CSR build (all types at once) ---
    hipMemsetAsync(bucket_cnt, 0, NUM_T * NB * sizeof(int), stream);
    convert_x<<<12500, 256, 0, stream>>>(x, xb);
    convert_W<<<dim3(256, NUM_T), 256, 0, stream>>>(Ws, Wt);
    p1_hist<<<dim3(P1_BLOCKS, NUM_T), 256, 0, stream>>>(adj, bucket_cnt);
    p1_scan<<<1, 128, 0, stream>>>(bucket_cnt, bucket_ptr, bucket_cur);
    p1_scatter<<<dim3(P1_BLOCKS, NUM_T), 256, 0, stream>>>(adj, bucket_cur, part);
    p2_csr<<<dim3(NB_USED, NUM_T), 256, 0, stream>>>(part, bucket_ptr, row_ptr,
                                                     csr_src);

    // --- all 3 gemms in one dispatch, 128x128 tiles (overwrites part alias) ---
    gemm_fused<<<dim3(MT_BLOCKS, 2, NUM_T), 256, 0, stream>>>(xb, Wt, H);

    // --- el/er from H (memory-bound, L3-resident) ---
    compute_elr<<<dim3(GATHER_BLOCKS, NUM_T), 256, 0, stream>>>(H, a_l, a_r,
                                                                el, er);

    // --- gather all types + semantic combine fused, fp32 out ---
    gat_gather_all<<<GATHER_BLOCKS, 256, 0, stream>>>(
        csr_src, row_ptr, el, er, H, bias, att_w, att_b, out);
}